// Round 1
// baseline (13457.736 us; speedup 1.0000x reference)
//
#include <hip/hip_runtime.h>

// ---------------- problem constants ----------------
#define BATCH    4096
#define HDIM     300      // hidden dim
#define GDIM     1200     // 4*H gate dim
#define TSTEPS   64
#define KDIM     600      // concat K = [x(300) | h(300)]
#define KPAD     608      // padded to 19*32
#define NKT      19       // K tiles of 32
#define NTILES   75       // N tiles of 16 (1200/16)
#define ASTRIDE  616      // LDS activation row stride (f16 elems): 308 dwords = 20 mod 32 -> 2-way max
#define OUTSTRIDE (TSTEPS*HDIM)   // 19200
#define ROWS_PER_BLOCK 16
#define NWAVES   8        // 512 threads
#define TILES_PER_WAVE 10 // ceil(75/8)

typedef _Float16 half8  __attribute__((ext_vector_type(8)));
typedef float    floatx4 __attribute__((ext_vector_type(4)));

// packed weight stream: elem index = ((l*NTILES + tile)*NKT + kt)*512 + lane*8 + j
//   value = Wcat_l[n][k],  n = tile*16 + (lane&15),  k = kt*32 + (lane>>4)*8 + j
//   n is gate-interleaved packed col: n = 4*hcol + gate  (gate order i,f,g,o)
//   Wcat_l[n][k] = k<300 ? W_ih[gate*300+hcol][k] : k<600 ? W_hh[gate*300+hcol][k-300] : 0
#define WP_LAYER_ELEMS ((size_t)NTILES * NKT * 512)

__global__ void pack_weights(const float* __restrict__ Wih0, const float* __restrict__ Whh0,
                             const float* __restrict__ Wih1, const float* __restrict__ Whh1,
                             _Float16* __restrict__ wp) {
    int idx = blockIdx.x * 256 + threadIdx.x;          // one (l,tile,kt,lane) chunk of 8
    const int total = 2 * NTILES * NKT * 64;
    if (idx >= total) return;
    int lane  = idx & 63;
    int rest  = idx >> 6;
    int kt    = rest % NKT;
    int rest2 = rest / NKT;
    int tile  = rest2 % NTILES;
    int l     = rest2 / NTILES;
    const float* Wih = l ? Wih1 : Wih0;
    const float* Whh = l ? Whh1 : Whh0;
    int n    = tile * 16 + (lane & 15);
    int hcol = n >> 2, gate = n & 3;
    int jrow = gate * 300 + hcol;
    int k0   = kt * 32 + (lane >> 4) * 8;
    half8 v8;
#pragma unroll
    for (int j = 0; j < 8; ++j) {
        int k = k0 + j;
        float v = 0.f;
        if (k < 300)      v = Wih[jrow * 300 + k];
        else if (k < 600) v = Whh[jrow * 300 + (k - 300)];
        v8[j] = (_Float16)v;
    }
    *(half8*)(wp + (size_t)idx * 8) = v8;
}

__global__ void pack_bias(const float* __restrict__ bih0, const float* __restrict__ bhh0,
                          const float* __restrict__ bih1, const float* __restrict__ bhh1,
                          float* __restrict__ bp) {
    int idx = blockIdx.x * 256 + threadIdx.x;
    if (idx >= 2 * GDIM) return;
    int l = idx / GDIM, n = idx % GDIM;
    int hcol = n >> 2, gate = n & 3;
    int j = gate * 300 + hcol;
    bp[idx] = l ? (bih1[j] + bhh1[j]) : (bih0[j] + bhh0[j]);
}

__device__ __forceinline__ float sigmoid_f(float x) {
    return 1.f / (1.f + __expf(-x));
}
__device__ __forceinline__ float tanh_f(float x) {
    x = fminf(fmaxf(x, -15.f), 15.f);   // avoid inf/inf
    float e = __expf(2.f * x);
    return (e - 1.f) / (e + 1.f);
}

__global__ __launch_bounds__(512, 1)
void lstm_kernel(const float* __restrict__ z, const _Float16* __restrict__ wp,
                 const float* __restrict__ bp, float* __restrict__ out) {
    // A0: layer0 operand [x | h0], A1: layer1 operand [h0n | h1]
    __shared__ _Float16 A0[ROWS_PER_BLOCK * ASTRIDE];
    __shared__ _Float16 A1[ROWS_PER_BLOCK * ASTRIDE];
    __shared__ float    bias_lds[2 * GDIM];
    __shared__ __align__(16) float scratch[NWAVES * 16 * 20];

    const int tid  = threadIdx.x;
    const int wave = tid >> 6;
    const int lane = tid & 63;
    const int row0 = blockIdx.x * ROWS_PER_BLOCK;   // global batch row base

    // ---- init: A0 = [z | 0], A1 = 0 (at least cols 300..615 and K-pad) ----
    for (int i = tid; i < ROWS_PER_BLOCK * ASTRIDE; i += 512) {
        int r = i / ASTRIDE, c = i - r * ASTRIDE;
        float v = (c < HDIM) ? z[(size_t)(row0 + r) * HDIM + c] : 0.f;
        A0[i] = (_Float16)v;
        A1[i] = (_Float16)0.f;
    }
    for (int i = tid; i < 2 * GDIM; i += 512) bias_lds[i] = bp[i];
    __syncthreads();

    const int m    = lane & 15;   // C-frag col / A-frag row (batch row within block)
    const int quad = lane >> 4;
    float* myscr = scratch + wave * (16 * 20);

    float cs[2][TILES_PER_WAVE];
#pragma unroll
    for (int l = 0; l < 2; ++l)
#pragma unroll
        for (int i = 0; i < TILES_PER_WAVE; ++i) cs[l][i] = 0.f;

    for (int t = 0; t < TSTEPS; ++t) {
#pragma unroll
        for (int l = 0; l < 2; ++l) {
            const _Float16* Asrc = l ? A1 : A0;
            _Float16*       Adst = l ? A0 : A1;
            _Float16*       Aself = l ? A1 : A0;     // post-sync h writeback target
            const _Float16* wpl  = wp + (size_t)l * WP_LAYER_ELEMS;
            const float*    bl   = bias_lds + l * GDIM;
            float hreg[TILES_PER_WAVE];

#pragma unroll
            for (int i = 0; i < TILES_PER_WAVE; ++i) {
                const int tile = wave + 8 * i;
                if (tile < NTILES) {
                    floatx4 acc = {0.f, 0.f, 0.f, 0.f};
                    const _Float16* wt = wpl + (size_t)tile * (NKT * 512) + lane * 8;
                    const _Float16* arow = Asrc + m * ASTRIDE + quad * 8;
#pragma unroll
                    for (int kt = 0; kt < NKT; ++kt) {
                        half8 a = *(const half8*)(arow + kt * 32);
                        half8 b = *(const half8*)(wt + kt * 512);
                        acc = __builtin_amdgcn_mfma_f32_16x16x32_f16(a, b, acc, 0, 0, 0);
                    }
                    // ---- epilogue: realign gates through per-wave LDS scratch ----
                    // C-frag: this lane holds col=m (packed gate col tile*16+m), rows quad*4+r
                    float bn = bl[tile * 16 + m];
#pragma unroll
                    for (int r = 0; r < 4; ++r)
                        myscr[(quad * 4 + r) * 20 + m] = acc[r] + bn;
                    __builtin_amdgcn_wave_barrier();   // wave-internal LDS: keep order
                    // re-read: lane <-> (row=m, hl=quad): 4 consecutive = (i,f,g,o) of hcol
                    floatx4 pg = *(const floatx4*)(myscr + m * 20 + quad * 4);
                    float ig = sigmoid_f(pg.x);
                    float fg = sigmoid_f(pg.y);
                    float gg = tanh_f(pg.z);
                    float og = sigmoid_f(pg.w);
                    float c  = fg * cs[l][i] + ig * gg;
                    cs[l][i] = c;
                    float h  = og * tanh_f(c);
                    hreg[i]  = h;
                    int hcol = tile * 4 + quad;
                    // write h into the OTHER buffer's first half (next consumer's x/h0n slot)
                    Adst[m * ASTRIDE + hcol] = (_Float16)h;
                    if (l) {  // layer1: also the sequence output
                        __builtin_nontemporal_store(
                            h, out + (size_t)(row0 + m) * OUTSTRIDE + t * HDIM + hcol);
                    }
                }
            }
            __syncthreads();
            // now safe: everyone finished reading Asrc; write h into Asrc's recurrent slot
#pragma unroll
            for (int i = 0; i < TILES_PER_WAVE; ++i) {
                const int tile = wave + 8 * i;
                if (tile < NTILES) {
                    int hcol = tile * 4 + quad;
                    Aself[m * ASTRIDE + 300 + hcol] = (_Float16)hreg[i];
                }
            }
            // visibility of these writes to the next reader is guaranteed by the
            // next layer's / next step's __syncthreads before any read of them
        }
    }
}

extern "C" void kernel_launch(void* const* d_in, const int* in_sizes, int n_in,
                              void* d_out, int out_size, void* d_ws, size_t ws_size,
                              hipStream_t stream) {
    const float* z    = (const float*)d_in[0];
    const float* Wih0 = (const float*)d_in[1];
    const float* Whh0 = (const float*)d_in[2];
    const float* bih0 = (const float*)d_in[3];
    const float* bhh0 = (const float*)d_in[4];
    const float* Wih1 = (const float*)d_in[5];
    const float* Whh1 = (const float*)d_in[6];
    const float* bih1 = (const float*)d_in[7];
    const float* bhh1 = (const float*)d_in[8];
    float* out = (float*)d_out;

    _Float16* wp = (_Float16*)d_ws;
    float*    bpf = (float*)((char*)d_ws + 2 * WP_LAYER_ELEMS * sizeof(_Float16));

    // pack weights into MFMA B-fragment stream order (runs every call; d_ws is re-poisoned)
    {
        int total = 2 * NTILES * NKT * 64;
        pack_weights<<<(total + 255) / 256, 256, 0, stream>>>(Wih0, Whh0, Wih1, Whh1, wp);
    }
    pack_bias<<<(2 * GDIM + 255) / 256, 256, 0, stream>>>(bih0, bhh0, bih1, bhh1, bpf);

    lstm_kernel<<<BATCH / ROWS_PER_BLOCK, 512, 0, stream>>>(z, wp, bpf, out);
}

// Round 2
// 2333.123 us; speedup vs baseline: 5.7681x; 5.7681x over previous
//
#include <hip/hip_runtime.h>

// ---------------- problem constants ----------------
#define BATCH    4096
#define HDIM     300      // hidden dim
#define GDIM     1200     // 4*H gate dim
#define TSTEPS   64
#define NKT      19       // K tiles of 32 (K=600 padded to 608)
#define NTILES   75       // N tiles of 16 (1200/16)
#define ASTRIDE  616      // LDS activation row stride (f16): 308 dwords -> max 2-way bank alias
#define HSTRIDE  304      // f32 h/c stage row stride
#define OUTSTRIDE (TSTEPS*HDIM)   // 19200
#define ROWS     16
#define NWAVES   8
#define PFK      16       // K-chunks of next tile prefetched (double-buffered)

typedef _Float16 half8  __attribute__((ext_vector_type(8)));
typedef float    floatx4 __attribute__((ext_vector_type(4)));

// packed weight stream: elem index = ((l*NTILES + tile)*NKT + kt)*512 + lane*8 + j
//   value = Wcat_l[n][k],  n = tile*16 + (lane&15),  k = kt*32 + (lane>>4)*8 + j
//   n is gate-interleaved packed col: n = 4*hcol + gate  (gate order i,f,g,o)
#define WP_LAYER_ELEMS ((size_t)NTILES * NKT * 512)

__global__ void pack_weights(const float* __restrict__ Wih0, const float* __restrict__ Whh0,
                             const float* __restrict__ Wih1, const float* __restrict__ Whh1,
                             _Float16* __restrict__ wp) {
    int idx = blockIdx.x * 256 + threadIdx.x;
    const int total = 2 * NTILES * NKT * 64;
    if (idx >= total) return;
    int lane  = idx & 63;
    int rest  = idx >> 6;
    int kt    = rest % NKT;
    int rest2 = rest / NKT;
    int tile  = rest2 % NTILES;
    int l     = rest2 / NTILES;
    const float* Wih = l ? Wih1 : Wih0;
    const float* Whh = l ? Whh1 : Whh0;
    int n    = tile * 16 + (lane & 15);
    int hcol = n >> 2, gate = n & 3;
    int jrow = gate * 300 + hcol;
    int k0   = kt * 32 + (lane >> 4) * 8;
    half8 v8;
#pragma unroll
    for (int j = 0; j < 8; ++j) {
        int k = k0 + j;
        float v = 0.f;
        if (k < 300)      v = Wih[jrow * 300 + k];
        else if (k < 600) v = Whh[jrow * 300 + (k - 300)];
        v8[j] = (_Float16)v;
    }
    *(half8*)(wp + (size_t)idx * 8) = v8;
}

__global__ void pack_bias(const float* __restrict__ bih0, const float* __restrict__ bhh0,
                          const float* __restrict__ bih1, const float* __restrict__ bhh1,
                          float* __restrict__ bp) {
    int idx = blockIdx.x * 256 + threadIdx.x;
    if (idx >= 2 * GDIM) return;
    int l = idx / GDIM, n = idx % GDIM;
    int hcol = n >> 2, gate = n & 3;
    int j = gate * 300 + hcol;
    bp[idx] = l ? (bih1[j] + bhh1[j]) : (bih0[j] + bhh0[j]);
}

__device__ __forceinline__ float sigmoid_f(float x) {
    return 1.f / (1.f + __expf(-x));
}
__device__ __forceinline__ float tanh_f(float x) {
    x = fminf(fmaxf(x, -15.f), 15.f);
    float e = __expf(2.f * x);
    return (e - 1.f) / (e + 1.f);
}

__global__ __launch_bounds__(512, 2)
void lstm_kernel(const float* __restrict__ z, const _Float16* __restrict__ wp,
                 const float* __restrict__ bp, float* __restrict__ out) {
    __shared__ _Float16 A0[ROWS * ASTRIDE];      // layer0 operand [x | h0]
    __shared__ _Float16 A1[ROWS * ASTRIDE];      // layer1 operand [h0n | h1]
    __shared__ float    bias_lds[2 * GDIM];
    __shared__ __align__(16) float scratch[NWAVES * 16 * 20];
    __shared__ float    Hst[2][ROWS * HSTRIDE];  // f32 h stage (recurrent copy + out store)
    __shared__ float    Cst[2][ROWS * HSTRIDE];  // f32 cell state

    const int tid  = threadIdx.x;
    const int wave = tid >> 6;
    const int lane = tid & 63;
    const int row0 = blockIdx.x * ROWS;

    // ---- init ----
    for (int i = tid; i < ROWS * ASTRIDE; i += 512) {
        int r = i / ASTRIDE, c = i - r * ASTRIDE;
        A0[i] = (_Float16)((c < HDIM) ? z[(size_t)(row0 + r) * HDIM + c] : 0.f);
        A1[i] = (_Float16)0.f;
    }
    for (int i = tid; i < 2 * GDIM; i += 512) bias_lds[i] = bp[i];
    for (int i = tid; i < ROWS * HSTRIDE; i += 512) { Cst[0][i] = 0.f; Cst[1][i] = 0.f; }
    __syncthreads();

    const int m    = lane & 15;     // batch row within block
    const int quad = lane >> 4;
    float* myscr = scratch + wave * (16 * 20);
    const int NT = (82 - wave) / 8;                    // tiles this wave: 10,10,10,9,...
    const size_t tstep = (size_t)8 * NKT * 512;        // weight elems per tile-index step

    for (int t = 0; t < TSTEPS; ++t) {
#pragma unroll
        for (int l = 0; l < 2; ++l) {
            const _Float16* Asrc = l ? A1 : A0;
            _Float16*       Adst = l ? A0 : A1;        // next consumer's x-slot
            const _Float16* wpl  = wp + (size_t)l * WP_LAYER_ELEMS;
            const float*    bl   = bias_lds + l * GDIM;
            float* cst = Cst[l];
            float* hst = Hst[l];

            // ---- A fragments into registers: tile-invariant, 19 x half8 ----
            half8 areg[NKT];
            {
                const _Float16* arow = Asrc + m * ASTRIDE + quad * 8;
#pragma unroll
                for (int kt = 0; kt < NKT; ++kt) areg[kt] = *(const half8*)(arow + kt * 32);
            }

            const _Float16* wt = wpl + (size_t)wave * (NKT * 512) + lane * 8;

            auto process = [&](int i, half8 (&bc)[PFK], half8 (&bn)[PFK]) {
                const _Float16* wcur = wt + (size_t)i * tstep;
                // tail of current tile (3 chunks) — issued first, consumed last
                half8 bt[NKT - PFK];
#pragma unroll
                for (int kt = PFK; kt < NKT; ++kt)
                    bt[kt - PFK] = *(const half8*)(wcur + kt * 512);
                // prefetch next tile's first PFK chunks (stays in flight across this tile)
                if (i + 1 < NT) {
                    const _Float16* wnext = wcur + tstep;
#pragma unroll
                    for (int kt = 0; kt < PFK; ++kt)
                        bn[kt] = *(const half8*)(wnext + kt * 512);
                }
                floatx4 acc = {0.f, 0.f, 0.f, 0.f};
#pragma unroll
                for (int kt = 0; kt < PFK; ++kt)
                    acc = __builtin_amdgcn_mfma_f32_16x16x32_f16(areg[kt], bc[kt], acc, 0, 0, 0);
#pragma unroll
                for (int kt = PFK; kt < NKT; ++kt)
                    acc = __builtin_amdgcn_mfma_f32_16x16x32_f16(areg[kt], bt[kt - PFK], acc, 0, 0, 0);

                // ---- epilogue: realign gates via per-wave LDS scratch ----
                const int tile = wave + 8 * i;
                float bn_ = bl[tile * 16 + m];
#pragma unroll
                for (int r = 0; r < 4; ++r)
                    myscr[(quad * 4 + r) * 20 + m] = acc[r] + bn_;
                __builtin_amdgcn_wave_barrier();
                floatx4 pg = *(const floatx4*)(myscr + m * 20 + quad * 4);
                __builtin_amdgcn_wave_barrier();
                float ig = sigmoid_f(pg.x);
                float fg = sigmoid_f(pg.y);
                float gg = tanh_f(pg.z);
                float og = sigmoid_f(pg.w);
                const int hcol = tile * 4 + quad;
                float c = fg * cst[m * HSTRIDE + hcol] + ig * gg;
                cst[m * HSTRIDE + hcol] = c;
                float h = og * tanh_f(c);
                hst[m * HSTRIDE + hcol] = h;
                Adst[m * ASTRIDE + hcol] = (_Float16)h;   // other buffer: safe pre-sync
            };

            // prologue: prefetch tile 0's first PFK chunks
            half8 b0[PFK], b1[PFK];
#pragma unroll
            for (int kt = 0; kt < PFK; ++kt) b0[kt] = *(const half8*)(wt + kt * 512);

            int i = 0;
            while (true) {
                process(i, b0, b1); if (++i >= NT) break;
                process(i, b1, b0); if (++i >= NT) break;
            }

            __syncthreads();
            // post-sync: copy recurrent h (f16) into own buffer; layer1 also stores output
            if (l == 0) {
                for (int idx = tid; idx < ROWS * HDIM; idx += 512) {
                    int r = idx / HDIM, c = idx - r * HDIM;
                    A0[r * ASTRIDE + 300 + c] = (_Float16)Hst[0][r * HSTRIDE + c];
                }
            } else {
                for (int idx = tid; idx < ROWS * HDIM; idx += 512) {
                    int r = idx / HDIM, c = idx - r * HDIM;
                    float h = Hst[1][r * HSTRIDE + c];
                    A1[r * ASTRIDE + 300 + c] = (_Float16)h;
                    __builtin_nontemporal_store(
                        h, out + (size_t)(row0 + r) * OUTSTRIDE + (size_t)t * HDIM + c);
                }
            }
            // visibility of post-sync writes to their next readers is guaranteed by the
            // next layer-step's __syncthreads (reader reads only after passing it)
        }
    }
}

extern "C" void kernel_launch(void* const* d_in, const int* in_sizes, int n_in,
                              void* d_out, int out_size, void* d_ws, size_t ws_size,
                              hipStream_t stream) {
    const float* z    = (const float*)d_in[0];
    const float* Wih0 = (const float*)d_in[1];
    const float* Whh0 = (const float*)d_in[2];
    const float* bih0 = (const float*)d_in[3];
    const float* bhh0 = (const float*)d_in[4];
    const float* Wih1 = (const float*)d_in[5];
    const float* Whh1 = (const float*)d_in[6];
    const float* bih1 = (const float*)d_in[7];
    const float* bhh1 = (const float*)d_in[8];
    float* out = (float*)d_out;

    _Float16* wp  = (_Float16*)d_ws;
    float*    bpf = (float*)((char*)d_ws + 2 * WP_LAYER_ELEMS * sizeof(_Float16));

    {
        int total = 2 * NTILES * NKT * 64;
        pack_weights<<<(total + 255) / 256, 256, 0, stream>>>(Wih0, Whh0, Wih1, Whh1, wp);
    }
    pack_bias<<<(2 * GDIM + 255) / 256, 256, 0, stream>>>(bih0, bhh0, bih1, bhh1, bpf);

    lstm_kernel<<<BATCH / ROWS, 512, 0, stream>>>(z, wp, bpf, out);
}